// Round 9
// baseline (421.125 us; speedup 1.0000x reference)
//
#include <hip/hip_runtime.h>
#include <stdint.h>

#define NN 8192
#define NF 512
#define NH 256

typedef __bf16 bf16_t;
typedef bf16_t bf16x8 __attribute__((ext_vector_type(8)));
typedef float f32x4 __attribute__((ext_vector_type(4)));
typedef int i32x4 __attribute__((ext_vector_type(4)));

// round-to-nearest-even f32 -> bf16 bit pattern
__device__ __forceinline__ unsigned short f2bf(float f) {
  union { float f; unsigned u; } v; v.f = f;
  unsigned r = v.u + 0x7FFFu + ((v.u >> 16) & 1u);
  return (unsigned short)(r >> 16);
}

__device__ __forceinline__ float bf2f(unsigned short u) {
  union { unsigned u; float f; } v; v.u = (unsigned)u << 16;
  return v.f;
}

__device__ __forceinline__ int sum4b(unsigned u) {
  return (int)(signed char)(u) + (int)(signed char)(u >> 8) +
         (int)(signed char)(u >> 16) + (int)(signed char)(u >> 24);
}

// async global->LDS, 16B per lane; LDS dest is wave-uniform base + lane*16
__device__ __forceinline__ void gload16(const void* g, void* l) {
  __builtin_amdgcn_global_load_lds(
      (__attribute__((address_space(1))) void*)g,
      (__attribute__((address_space(3))) void*)l, 16, 0, 0);
}

// ---- fused prep: [0,8192): A8=i8(254*adj-127) + dinv; [8192,12288): xbf; [12288,13824): WTc ----
__global__ void fusedprep_kernel(const float* __restrict__ adj, const float* __restrict__ x,
                                 const float* __restrict__ W,
                                 signed char* __restrict__ A8, float* __restrict__ dinv,
                                 unsigned short* __restrict__ xbf,
                                 unsigned short* __restrict__ WTc,
                                 unsigned long long* __restrict__ sumv) {
  const int b = blockIdx.x, t = threadIdx.x;
  if (b < 8192) {
    if (b == 0 && t == 0) { sumv[0] = 0ull; sumv[1] = 0ull; }
    const int i = b;
    const float4* row = reinterpret_cast<const float4*>(adj + (long)i * NN);
    unsigned* orow = reinterpret_cast<unsigned*>(A8 + (long)i * NN);
    float s = 0.f;
#pragma unroll
    for (int it = 0; it < 8; ++it) {
      float4 a = row[it * 256 + t];
      s += a.x + a.y + a.z + a.w;
      int qx = (int)rintf(a.x * 254.f - 127.f);
      int qy = (int)rintf(a.y * 254.f - 127.f);
      int qz = (int)rintf(a.z * 254.f - 127.f);
      int qw = (int)rintf(a.w * 254.f - 127.f);
      orow[it * 256 + t] = (unsigned)(qx & 255) | ((unsigned)(qy & 255) << 8) |
                           ((unsigned)(qz & 255) << 16) | ((unsigned)(qw & 255) << 24);
    }
    for (int o = 32; o; o >>= 1) s += __shfl_down(s, o, 64);
    __shared__ float sm[4];
    if ((t & 63) == 0) sm[t >> 6] = s;
    __syncthreads();
    if (t == 0) {
      float d = fmaxf(sm[0] + sm[1] + sm[2] + sm[3], 1e-12f);
      dinv[i] = rsqrtf(d);
    }
  } else if (b < 12288) {
    const long idx4 = (long)(b - 8192) * 256 + t;
    float4 a = reinterpret_cast<const float4*>(x)[idx4];
    ushort4 o;
    o.x = f2bf(a.x); o.y = f2bf(a.y); o.z = f2bf(a.z); o.w = f2bf(a.w);
    reinterpret_cast<ushort4*>(xbf)[idx4] = o;
  } else {
    const int idx = (b - 12288) * 256 + t; // 393216
    const int c = idx >> 9, k = idx & 511;
    float val;
    if (c < 256) val = W[k * 256 + c] - W[262144 + k * 256 + c];
    else if (c < 512) val = W[131072 + k * 256 + (c - 256)];
    else val = W[262144 + k * 256 + (c - 512)];
    WTc[(long)c * 512 + k] = f2bf(val);
  }
}

// ================= i8 256x256 GEMM, R8's 2-barrier/tile interleaved schedule =================
// A [M][NN] i8 (row stride NN bytes); BT [Nout][NN] i8. Byte geometry IDENTICAL to the R8 bf16
// kernel (tile = 128 B of K, half = 64 B/row, frag = one b128/lane) -> same staging, swizzle,
// vmcnt ring, schedule; MFMA = mfma_i32_16x16x64_i8 (K=64/instr, 2x bf16 rate), nt = kLenB/128.
// Epilogue dequant: P = (i32 + 127*colsum[kz][col]) * invscale -> bf16 partial.
__device__ __forceinline__ i32x4 ldfragi(const signed char* h, int r, int l) {
  const int kb = ((l >> 4) * 16) ^ (((r >> 1) & 3) << 4);
  return *reinterpret_cast<const i32x4*>(h + r * 64 + kb);
}

__device__ __forceinline__ void stage_half8(const signed char* __restrict__ G,
                                            int gR0, long kByte, signed char* lbase,
                                            int w, int tid) {
  const int rr = tid >> 2;                 // dest row 0..127 (call 0) / +128 (call 1)
  const int kb = (tid & 3) * 16;           // dest byte col within 64B row
  const int sw = ((rr >> 1) & 3) << 4;     // read-side XOR pre-applied to global source
  gload16(G + (long)(gR0 + rr) * NN + kByte + (kb ^ sw), lbase + w * 1024);
  gload16(G + (long)(gR0 + 128 + rr) * NN + kByte + (kb ^ sw), lbase + 8192 + w * 1024);
}

#define BAR() __builtin_amdgcn_s_barrier()
#define SCHED0() __builtin_amdgcn_sched_barrier(0)
#define LGKM0() do { asm volatile("s_waitcnt lgkmcnt(0)" ::: "memory"); SCHED0(); } while (0)

__global__ __launch_bounds__(512) void gemm8i(
    const signed char* __restrict__ A, const signed char* __restrict__ BT,
    const int kLenB, const int Nout, const int* __restrict__ colsum,
    const float invscale, unsigned short* __restrict__ Pb) {
  __shared__ signed char As[2][2][256 * 64];
  __shared__ signed char Bs[2][2][256 * 64];
  const int tid = threadIdx.x;
  const int w = tid >> 6, l = tid & 63;
  const int wr = w >> 2, wc = w & 3;
  const int nwg2d = gridDim.x * gridDim.y;
  const int lin = blockIdx.x + gridDim.x * blockIdx.y;
  const int wg = (lin & 7) * (nwg2d >> 3) + (lin >> 3);
  const int bx = wg % gridDim.x, by = wg / gridDim.x;
  const int aRow0 = by * 256, bRow0 = bx * 256;
  const long kbegB = (long)blockIdx.z * kLenB;
  const int nt = kLenB >> 7;
  i32x4 acc[8][4] = {};

  // prologue: t0.kh0(A,B), t0.kh1(A,B), t1.kh0(A,B) = 12 loads/wave
  stage_half8(A, aRow0, kbegB, &As[0][0][0], w, tid);
  stage_half8(BT, bRow0, kbegB, &Bs[0][0][0], w, tid);
  stage_half8(A, aRow0, kbegB + 64, &As[0][1][0], w, tid);
  stage_half8(BT, bRow0, kbegB + 64, &Bs[0][1][0], w, tid);
  {
    const int t1 = (nt > 1) ? 1 : 0;
    stage_half8(A, aRow0, kbegB + (long)t1 * 128, &As[1][0][0], w, tid);
    stage_half8(BT, bRow0, kbegB + (long)t1 * 128, &Bs[1][0][0], w, tid);
  }
  asm volatile("s_waitcnt vmcnt(4)" ::: "memory");
  SCHED0();
  BAR(); SCHED0();

  i32x4 av[8], bv[4];
  const int la = l & 15;
  for (int t = 0; t < nt; ++t) {
    const int d = t & 1;
    const signed char* Ah0 = &As[d][0][0];
    const signed char* Ah1 = &As[d][1][0];
    const signed char* Bh0 = &Bs[d][0][0];
    const signed char* Bh1 = &Bs[d][1][0];
    const int tt1 = (t + 1 < nt) ? t + 1 : nt - 1;
    const int tt2 = (t + 2 < nt) ? t + 2 : nt - 1;

#pragma unroll
    for (int m = 0; m < 8; ++m) av[m] = ldfragi(Ah0, wr * 128 + m * 16 + la, l);
#pragma unroll
    for (int n = 0; n < 4; ++n) bv[n] = ldfragi(Bh0, wc * 64 + n * 16 + la, l);
    stage_half8(A, aRow0, kbegB + (long)tt1 * 128 + 64, &As[d ^ 1][1][0], w, tid);
    stage_half8(BT, bRow0, kbegB + (long)tt1 * 128 + 64, &Bs[d ^ 1][1][0], w, tid);
    LGKM0();
    BAR(); SCHED0();          // all waves' kh0 reads done -> [d][0] overwrite-safe
    stage_half8(A, aRow0, kbegB + (long)tt2 * 128, &As[d][0][0], w, tid);
    stage_half8(BT, bRow0, kbegB + (long)tt2 * 128, &Bs[d][0][0], w, tid);
    __builtin_amdgcn_s_setprio(1);
#pragma unroll
    for (int m = 0; m < 8; ++m) {
#pragma unroll
      for (int n = 0; n < 4; ++n)
        acc[m][n] = __builtin_amdgcn_mfma_i32_16x16x64_i8(av[m], bv[n], acc[m][n], 0, 0, 0);
      av[m] = ldfragi(Ah1, wr * 128 + m * 16 + la, l);
    }
    __builtin_amdgcn_s_setprio(0);
#pragma unroll
    for (int n = 0; n < 4; ++n) bv[n] = ldfragi(Bh1, wc * 64 + n * 16 + la, l);
    LGKM0();
    __builtin_amdgcn_s_setprio(1);
#pragma unroll
    for (int m = 0; m < 8; ++m)
#pragma unroll
      for (int n = 0; n < 4; ++n)
        acc[m][n] = __builtin_amdgcn_mfma_i32_16x16x64_i8(av[m], bv[n], acc[m][n], 0, 0, 0);
    __builtin_amdgcn_s_setprio(0);
    asm volatile("s_waitcnt vmcnt(4)" ::: "memory");
    SCHED0();
    BAR(); SCHED0();
  }

  // C elem (row = base + (l>>4)*4 + j, col = base + (l&15)); dtype-independent map
  unsigned short* Pk = Pb + (long)blockIdx.z * NN * Nout;
  const int kz = blockIdx.z;
  const int lr = (l >> 4) * 4;
#pragma unroll
  for (int m = 0; m < 8; ++m)
#pragma unroll
    for (int n = 0; n < 4; ++n) {
      const int rowb = aRow0 + wr * 128 + m * 16 + lr;
      const int col = bRow0 + wc * 64 + n * 16 + la;
      const int cs = colsum[kz * Nout + col];
#pragma unroll
      for (int j = 0; j < 4; ++j)
        Pk[(long)(rowb + j) * Nout + col] = f2bf((float)(acc[m][n][j] + 127 * cs) * invscale);
    }
}

// ---------------- m97-style 128x128 bf16 GEMM for the small W-projection ----------------
// Epilogue: col<256 -> Q0 f32; col>=256 -> q12T[col-256][row] = i8(round(2048*dinv[row]*v))
__global__ __launch_bounds__(256) void gemm_w(
    const unsigned short* __restrict__ A, const unsigned short* __restrict__ BT,
    const int lda, const int ldbt, const int kLen, const int Nout,
    float* __restrict__ Q0, signed char* __restrict__ q12T,
    const float* __restrict__ dinv) {
  __shared__ unsigned short As[128 * 64];
  __shared__ unsigned short Bs[128 * 64];
  const int tid = threadIdx.x;
  const int w = tid >> 6, l = tid & 63;
  const int wr = w >> 1, wc = w & 1;
  const int nwg2d = gridDim.x * gridDim.y;
  const int lin = blockIdx.x + gridDim.x * blockIdx.y;
  const int wg = (lin & 7) * (nwg2d >> 3) + (lin >> 3);
  const int bx = wg % gridDim.x, by = wg / gridDim.x;
  const int aRow0 = by * 128, bRow0 = bx * 128;
  const int lrow8 = l >> 3;
  const int lk8 = (l & 7) * 8;
  f32x4 acc[4][4] = {};

  for (int k0 = 0; k0 < kLen; k0 += 64) {
    __syncthreads();
#pragma unroll
    for (int i = 0; i < 4; ++i) {
      const int ch = w * 4 + i;
      gload16(A + (long)(aRow0 + ch * 8 + lrow8) * lda + k0 + lk8, &As[ch * 512]);
      gload16(BT + (long)(bRow0 + ch * 8 + lrow8) * ldbt + k0 + lk8, &Bs[ch * 512]);
    }
    __syncthreads();
#pragma unroll
    for (int ks = 0; ks < 2; ++ks) {
      bf16x8 av[4], bv[4];
#pragma unroll
      for (int m = 0; m < 4; ++m)
        av[m] = *reinterpret_cast<const bf16x8*>(
            &As[(wr * 64 + m * 16 + (l & 15)) * 64 + ks * 32 + (l >> 4) * 8]);
#pragma unroll
      for (int n = 0; n < 4; ++n)
        bv[n] = *reinterpret_cast<const bf16x8*>(
            &Bs[(wc * 64 + n * 16 + (l & 15)) * 64 + ks * 32 + (l >> 4) * 8]);
#pragma unroll
      for (int m = 0; m < 4; ++m)
#pragma unroll
        for (int n = 0; n < 4; ++n)
          acc[m][n] = __builtin_amdgcn_mfma_f32_16x16x32_bf16(av[m], bv[n], acc[m][n], 0, 0, 0);
    }
  }

  const int lr = (l >> 4) * 4;
  const int lc = l & 15;
#pragma unroll
  for (int m = 0; m < 4; ++m)
#pragma unroll
    for (int n = 0; n < 4; ++n) {
      const int rowb = aRow0 + wr * 64 + m * 16 + lr;
      const int col = bRow0 + wc * 64 + n * 16 + lc;
      if (col < 256) {
#pragma unroll
        for (int j = 0; j < 4; ++j)
          Q0[(long)(rowb + j) * 256 + col] = acc[m][n][j];
      } else {
        signed char pv[4];
#pragma unroll
        for (int j = 0; j < 4; ++j) {
          float q = rintf(2048.f * dinv[rowb + j] * acc[m][n][j]);
          pv[j] = (signed char)(int)fminf(fmaxf(q, -127.f), 127.f);
        }
        *reinterpret_cast<int*>(&q12T[(long)(col - 256) * NN + rowb]) =
            *reinterpret_cast<int*>(pv);
      }
    }
}

// ---- colsumA: cs[kz][c] = sum over j in kz-chunk (2048) of q12T[c][j], kz<4, c<512 ----
__global__ void colsumA_kernel(const signed char* __restrict__ q12T, int* __restrict__ cs) {
  const int c = blockIdx.x, t = threadIdx.x;
  const uint4* row = reinterpret_cast<const uint4*>(q12T + (long)c * NN);
  uint4 v0 = row[t * 2], v1 = row[t * 2 + 1]; // bytes [32t, 32t+32)
  int s = sum4b(v0.x) + sum4b(v0.y) + sum4b(v0.z) + sum4b(v0.w) +
          sum4b(v1.x) + sum4b(v1.y) + sum4b(v1.z) + sum4b(v1.w);
  for (int o = 32; o; o >>= 1) s += __shfl_down(s, o, 64);
  if ((t & 63) == 0) cs[(t >> 6) * 512 + c] = s; // wave w == kz
}

// ---- colsumB: cs[kz][c] = sum over j in kz-chunk (1024) of bT2[c][j], kz<8, c<256 ----
__global__ void colsumB_kernel(const signed char* __restrict__ bT2, int* __restrict__ cs) {
  const int c = blockIdx.x, t = threadIdx.x;
  const uint4* row = reinterpret_cast<const uint4*>(bT2 + (long)c * NN);
  uint4 v0 = row[t * 2], v1 = row[t * 2 + 1];
  int s = sum4b(v0.x) + sum4b(v0.y) + sum4b(v0.z) + sum4b(v0.w) +
          sum4b(v1.x) + sum4b(v1.y) + sum4b(v1.z) + sum4b(v1.w);
  for (int o = 16; o; o >>= 1) s += __shfl_down(s, o, 64);
  if ((t & 31) == 0) cs[(t >> 5) * 256 + c] = s; // half-wave == kz
}

// ---- reduceA: S = sum_z Pb[z] over [8192][512] ----
// c<256: s1[r][c] = dinv[r]*S.  c>=256: bT2[c-256][r] = i8(round(131072*dinv^2*S)) (transposed)
__global__ void reduceA_kernel(const unsigned short* __restrict__ Pb, const int ks,
                               const float* __restrict__ dinv,
                               float* __restrict__ s1, signed char* __restrict__ bT2) {
  __shared__ float tile[64][65];
  const int c0 = blockIdx.x * 64;
  const int r0 = blockIdx.y * 64;
  const int t = threadIdx.x;
  if (c0 < 256) {
#pragma unroll
    for (int it = 0; it < 16; ++it) {
      int e = it * 256 + t;
      int r = e >> 6, c = e & 63;
      long off = (long)(r0 + r) * 512 + c0 + c;
      float S = 0.f;
      for (int z = 0; z < ks; ++z) S += bf2f(Pb[(long)z * NN * 512 + off]);
      s1[(long)(r0 + r) * 256 + c0 + c] = dinv[r0 + r] * S;
    }
  } else {
#pragma unroll
    for (int it = 0; it < 16; ++it) {
      int e = it * 256 + t;
      int r = e >> 6, c = e & 63;
      long off = (long)(r0 + r) * 512 + c0 + c;
      float S = 0.f;
      for (int z = 0; z < ks; ++z) S += bf2f(Pb[(long)z * NN * 512 + off]);
      const float di = dinv[r0 + r];
      tile[r][c] = di * di * S;
    }
    __syncthreads();
#pragma unroll
    for (int it = 0; it < 16; ++it) {
      int e = it * 256 + t;
      int rr = e >> 6, cc = e & 63;
      float q = rintf(131072.f * tile[cc][rr]);
      bT2[(long)(c0 - 256 + rr) * NN + r0 + cc] =
          (signed char)(int)fminf(fmaxf(q, -127.f), 127.f);
    }
  }
}

// ---- combine: h = relu(Q0 - s1 + 2*dinv[i]*sum_z P_B[z] + cheb_b); v = h @ gc2_W ----
// also accumulates sumv[c] = sum_i v[i][c] as exact 2^20 fixed-point (deterministic atomics)
__global__ void combine_u_kernel(const float* __restrict__ Q0, const float* __restrict__ s1,
                                 const unsigned short* __restrict__ Pb, const int ks,
                                 const float* __restrict__ dinv, const float* __restrict__ chebb,
                                 const float* __restrict__ gw, float* __restrict__ v,
                                 unsigned long long* __restrict__ sumv) {
  const int i = blockIdx.x, t = threadIdx.x;
  float S = 0.f;
  for (int z = 0; z < ks; ++z) S += bf2f(Pb[(long)z * NN * 256 + (long)i * 256 + t]);
  float hv = Q0[(long)i * 256 + t] - s1[(long)i * 256 + t] + 2.f * dinv[i] * S + chebb[t];
  hv = hv > 0.f ? hv : 0.f;
  float p0 = hv * gw[t * 2];
  float p1 = hv * gw[t * 2 + 1];
  for (int o = 32; o; o >>= 1) {
    p0 += __shfl_down(p0, o, 64);
    p1 += __shfl_down(p1, o, 64);
  }
  __shared__ float s0[4], s1s[4];
  if ((t & 63) == 0) { s0[t >> 6] = p0; s1s[t >> 6] = p1; }
  __syncthreads();
  if (t == 0) {
    float v0 = s0[0] + s0[1] + s0[2] + s0[3];
    float v1 = s1s[0] + s1s[1] + s1s[2] + s1s[3];
    v[i * 2] = v0;
    v[i * 2 + 1] = v1;
    atomicAdd(&sumv[0], (unsigned long long)(long long)llrintf(v0 * 1048576.f));
    atomicAdd(&sumv[1], (unsigned long long)(long long)llrintf(v1 * 1048576.f));
  }
}

// ---- logits: 8 rows/block; logits[i][c] = (sum_j q_a[i][j]*v[j][c] + 127*sumv[c])/254 + gb[c] ----
__global__ void logits8_kernel(const signed char* __restrict__ A8,
                               const float* __restrict__ v,
                               const unsigned long long* __restrict__ sumv,
                               const float* __restrict__ gb, float* __restrict__ logits) {
  const int g = blockIdx.x; // 1024 groups of 8 rows
  const int t = threadIdx.x;
  const float4* vv = reinterpret_cast<const float4*>(v);
  float a0[8] = {}, a1[8] = {};
#pragma unroll
  for (int it = 0; it < 2; ++it) {
    const int idx = it * 256 + t; // uint4 index within a row (512/row, 16 i8 each)
    float4 vs[8];
#pragma unroll
    for (int q = 0; q < 8; ++q) vs[q] = vv[idx * 8 + q];
#pragma unroll
    for (int r = 0; r < 8; ++r) {
      uint4 pk = reinterpret_cast<const uint4*>(A8 + (long)(g * 8 + r) * NN)[idx];
      unsigned uu[4] = {pk.x, pk.y, pk.z, pk.w};
#pragma unroll
      for (int q = 0; q < 4; ++q) {
        const unsigned u = uu[q];
        const float f0 = (float)(signed char)(u);
        const float f1 = (float)(signed char)(u >> 8);
        const float f2 = (float)(signed char)(u >> 16);
        const float f3 = (float)(signed char)(u >> 24);
        const float4 va = vs[q * 2], vb = vs[q * 2 + 1];
        a0[r] += f0 * va.x + f1 * va.z + f2 * vb.x + f3 * vb.z;
        a1[r] += f0 * va.y + f1 * va.w + f2 * vb.y + f3 * vb.w;
      }
    }
  }
  __shared__ float sm0[8][4], sm1[8][4];
#pragma unroll
  for (int r = 0; r < 8; ++r) {
    float x0 = a0[r], x1 = a1[r];
    for (int o = 32; o; o >>= 1) {
      x0 += __shfl_down(x0, o, 64);
      x1 += __shfl_down(x1, o, 64);
    }
    if ((t & 63) == 0) { sm0[r][t >> 6] = x0; sm1[r][t >> 6] = x1; }
  }
  __syncthreads();
  if (t < 8) {
    const float sv0 = (float)(long long)sumv[0] * 9.5367431640625e-7f; // 2^-20
    const float sv1 = (float)(long long)sumv[1] * 9.5367431640625e-7f;
    const float d0 = sm0[t][0] + sm0[t][1] + sm0[t][2] + sm0[t][3];
    const float d1 = sm1[t][0] + sm1[t][1] + sm1[t][2] + sm1[t][3];
    logits[(g * 8 + t) * 2] = (d0 + 127.f * sv0) * (1.f / 254.f) + gb[0];
    logits[(g * 8 + t) * 2 + 1] = (d1 + 127.f * sv1) * (1.f / 254.f) + gb[1];
  }
}

// ---------------- out[c] = max_i logits[i][c] ----------------
__global__ void maxpool_kernel(const float* __restrict__ logits, float* __restrict__ out) {
  const int t = threadIdx.x;
  float m0 = -3.4e38f, m1 = -3.4e38f;
  for (int i = t; i < NN; i += 256) {
    m0 = fmaxf(m0, logits[i * 2]);
    m1 = fmaxf(m1, logits[i * 2 + 1]);
  }
  for (int o = 32; o; o >>= 1) {
    m0 = fmaxf(m0, __shfl_down(m0, o, 64));
    m1 = fmaxf(m1, __shfl_down(m1, o, 64));
  }
  __shared__ float s0[4], s1[4];
  if ((t & 63) == 0) { s0[t >> 6] = m0; s1[t >> 6] = m1; }
  __syncthreads();
  if (t == 0) {
    out[0] = fmaxf(fmaxf(s0[0], s0[1]), fmaxf(s0[2], s0[3]));
    out[1] = fmaxf(fmaxf(s1[0], s1[1]), fmaxf(s1[2], s1[3]));
  }
}

extern "C" void kernel_launch(void* const* d_in, const int* in_sizes, int n_in,
                              void* d_out, int out_size, void* d_ws, size_t ws_size,
                              hipStream_t stream) {
  (void)in_sizes; (void)n_in; (void)out_size; (void)ws_size;
  const float* x = (const float*)d_in[0];       // [8192,512]
  const float* adj = (const float*)d_in[1];     // [8192,8192]
  const float* cheb_W = (const float*)d_in[2];  // [3,512,256]
  const float* cheb_b = (const float*)d_in[3];  // [256]
  const float* gc2_W = (const float*)d_in[4];   // [256,2]
  const float* gc2_b = (const float*)d_in[5];   // [2]
  float* out = (float*)d_out;                   // [2]

  char* ws = (char*)d_ws;
  signed char* A8      = (signed char*)(ws);                  // 64 MiB i8 adj (q=254a-127)
  unsigned short* xbf  = (unsigned short*)(ws + 67108864L);   // 8 MiB
  unsigned short* WTc  = (unsigned short*)(ws + 75497472L);   // 768 KiB [768][512]
  float* Q0            = (float*)(ws + 76546048L);            // 8 MiB f32 [8192][256]
  signed char* q12T    = (signed char*)(ws + 84934656L);      // 4 MiB i8 [512][8192]
  float* s1            = (float*)(ws + 89128960L);            // 8 MiB f32 [8192][256]
  signed char* bT2     = (signed char*)(ws + 97517568L);      // 2 MiB i8 [256][8192]
  float* dinv          = (float*)(ws + 99614720L);            // 32 KiB
  float* v             = (float*)(ws + 99647488L);            // 64 KiB
  float* logits        = (float*)(ws + 99713024L);            // 64 KiB
  int* colsumA         = (int*)(ws + 99778560L);              // 8 KiB [4][512]
  int* colsumB         = (int*)(ws + 99786752L);              // 8 KiB [8][256]
  unsigned long long* sumv = (unsigned long long*)(ws + 99794944L); // 16 B
  unsigned short* P    = (unsigned short*)(ws + 99803136L);   // 32 MiB bf16 partials

  const int ksA = 4, ksB = 8;
  const float invA = 1.f / (254.f * 2048.f);
  const float invB = 1.f / (254.f * 131072.f);

  // 1) A8 = i8(adj); dinv; xbf; WTc; zero sumv
  fusedprep_kernel<<<dim3(13824), dim3(256), 0, stream>>>(adj, x, cheb_W, A8, dinv, xbf, WTc, sumv);
  // 2) gemm_w: Q = xbf @ Wcat -> Q0 f32 (cols<256), q12T = i8(2048*dinv.*[q1|q2])^T
  gemm_w<<<dim3(6, 64, 1), dim3(256), 0, stream>>>(xbf, WTc, 512, 512, 512, 768, Q0, q12T, dinv);
  // 3) colsumA[kz][c]
  colsumA_kernel<<<dim3(512), dim3(256), 0, stream>>>(q12T, colsumA);
  // 4) GEMM_A (i8): P[kz] = dequant partials of adj @ (dinv.*[q1|q2])  [8192][512]
  gemm8i<<<dim3(2, 32, ksA), dim3(512), 0, stream>>>(A8, q12T, NN / ksA, 512, colsumA, invA, P);
  // 5) reduceA: s1 = dinv.*S[:,0:256]; bT2 = i8(131072*dinv^2.*S[:,256:512])^T
  reduceA_kernel<<<dim3(8, 128), dim3(256), 0, stream>>>(P, ksA, dinv, s1, bT2);
  // 6) colsumB[kz][c]
  colsumB_kernel<<<dim3(256), dim3(256), 0, stream>>>(bT2, colsumB);
  // 7) GEMM_B (i8): P[kz] = dequant partials of adj @ (dinv^2.*S2)  [8192][256]
  gemm8i<<<dim3(1, 32, ksB), dim3(512), 0, stream>>>(A8, bT2, NN / ksB, 256, colsumB, invB, P);
  // 8) h = relu(Q0 - s1 + 2*dinv.*sumP + b); v = h @ gc2_W; sumv fixed-point
  combine_u_kernel<<<dim3(NN), dim3(256), 0, stream>>>(Q0, s1, P, ksB, dinv, cheb_b, gc2_W, v, sumv);
  // 9) logits = (q_adj @ v + 127*sumv)/254 + b
  logits8_kernel<<<dim3(1024), dim3(256), 0, stream>>>(A8, v, sumv, gc2_b, logits);
  maxpool_kernel<<<dim3(1), dim3(256), 0, stream>>>(logits, out);
}

// Round 10
// 245.186 us; speedup vs baseline: 1.7176x; 1.7176x over previous
//
#include <hip/hip_runtime.h>
#include <stdint.h>

#define NN 8192
#define NF 512
#define NH 256

typedef __bf16 bf16_t;
typedef bf16_t bf16x8 __attribute__((ext_vector_type(8)));
typedef float f32x4 __attribute__((ext_vector_type(4)));
typedef int i32x4 __attribute__((ext_vector_type(4)));

// round-to-nearest-even f32 -> bf16 bit pattern
__device__ __forceinline__ unsigned short f2bf(float f) {
  union { float f; unsigned u; } v; v.f = f;
  unsigned r = v.u + 0x7FFFu + ((v.u >> 16) & 1u);
  return (unsigned short)(r >> 16);
}

__device__ __forceinline__ float bf2f(unsigned short u) {
  union { unsigned u; float f; } v; v.u = (unsigned)u << 16;
  return v.f;
}

__device__ __forceinline__ int sum4b(unsigned u) {
  return (int)(signed char)(u) + (int)(signed char)(u >> 8) +
         (int)(signed char)(u >> 16) + (int)(signed char)(u >> 24);
}

// async global->LDS, 16B per lane; LDS dest is wave-uniform base + lane*16
__device__ __forceinline__ void gload16(const void* g, void* l) {
  __builtin_amdgcn_global_load_lds(
      (__attribute__((address_space(1))) void*)g,
      (__attribute__((address_space(3))) void*)l, 16, 0, 0);
}

// ---- fused prep: [0,8192): A8=i8(254*adj-127) + dinv; [8192,12288): xbf; [12288,13824): WTc ----
__global__ void fusedprep_kernel(const float* __restrict__ adj, const float* __restrict__ x,
                                 const float* __restrict__ W,
                                 signed char* __restrict__ A8, float* __restrict__ dinv,
                                 unsigned short* __restrict__ xbf,
                                 unsigned short* __restrict__ WTc) {
  const int b = blockIdx.x, t = threadIdx.x;
  if (b < 8192) {
    const int i = b;
    const float4* row = reinterpret_cast<const float4*>(adj + (long)i * NN);
    unsigned* orow = reinterpret_cast<unsigned*>(A8 + (long)i * NN);
    float s = 0.f;
#pragma unroll
    for (int it = 0; it < 8; ++it) {
      float4 a = row[it * 256 + t];
      s += a.x + a.y + a.z + a.w;
      int qx = (int)rintf(a.x * 254.f - 127.f);
      int qy = (int)rintf(a.y * 254.f - 127.f);
      int qz = (int)rintf(a.z * 254.f - 127.f);
      int qw = (int)rintf(a.w * 254.f - 127.f);
      orow[it * 256 + t] = (unsigned)(qx & 255) | ((unsigned)(qy & 255) << 8) |
                           ((unsigned)(qz & 255) << 16) | ((unsigned)(qw & 255) << 24);
    }
    for (int o = 32; o; o >>= 1) s += __shfl_down(s, o, 64);
    __shared__ float sm[4];
    if ((t & 63) == 0) sm[t >> 6] = s;
    __syncthreads();
    if (t == 0) {
      float d = fmaxf(sm[0] + sm[1] + sm[2] + sm[3], 1e-12f);
      dinv[i] = rsqrtf(d);
    }
  } else if (b < 12288) {
    const long idx4 = (long)(b - 8192) * 256 + t;
    float4 a = reinterpret_cast<const float4*>(x)[idx4];
    ushort4 o;
    o.x = f2bf(a.x); o.y = f2bf(a.y); o.z = f2bf(a.z); o.w = f2bf(a.w);
    reinterpret_cast<ushort4*>(xbf)[idx4] = o;
  } else {
    const int idx = (b - 12288) * 256 + t; // 393216
    const int c = idx >> 9, k = idx & 511;
    float val;
    if (c < 256) val = W[k * 256 + c] - W[262144 + k * 256 + c];
    else if (c < 512) val = W[131072 + k * 256 + (c - 256)];
    else val = W[262144 + k * 256 + (c - 512)];
    WTc[(long)c * 512 + k] = f2bf(val);
  }
}

// ================= i8 256x256 GEMM, 2-barrier/tile interleaved schedule =================
// A [M][NN] i8; BT [Nout][NN] i8. Tile = 128 B of K, half = 64 B/row, frag = one b128/lane.
// MFMA = mfma_i32_16x16x64_i8 (K=64/instr, 2x bf16 rate), nt = kLenB/128.
// Epilogue dequant: P = (i32 + 127*colsum[kz][col]) * invscale -> bf16 partial.
__device__ __forceinline__ i32x4 ldfragi(const signed char* h, int r, int l) {
  const int kb = ((l >> 4) * 16) ^ (((r >> 1) & 3) << 4);
  return *reinterpret_cast<const i32x4*>(h + r * 64 + kb);
}

__device__ __forceinline__ void stage_half8(const signed char* __restrict__ G,
                                            int gR0, long kByte, signed char* lbase,
                                            int w, int tid) {
  const int rr = tid >> 2;                 // dest row 0..127 (call 0) / +128 (call 1)
  const int kb = (tid & 3) * 16;           // dest byte col within 64B row
  const int sw = ((rr >> 1) & 3) << 4;     // read-side XOR pre-applied to global source
  gload16(G + (long)(gR0 + rr) * NN + kByte + (kb ^ sw), lbase + w * 1024);
  gload16(G + (long)(gR0 + 128 + rr) * NN + kByte + (kb ^ sw), lbase + 8192 + w * 1024);
}

#define BAR() __builtin_amdgcn_s_barrier()
#define SCHED0() __builtin_amdgcn_sched_barrier(0)
#define LGKM0() do { asm volatile("s_waitcnt lgkmcnt(0)" ::: "memory"); SCHED0(); } while (0)

__global__ __launch_bounds__(512) void gemm8i(
    const signed char* __restrict__ A, const signed char* __restrict__ BT,
    const int kLenB, const int Nout, const int* __restrict__ colsum,
    const float invscale, unsigned short* __restrict__ Pb) {
  __shared__ signed char As[2][2][256 * 64];
  __shared__ signed char Bs[2][2][256 * 64];
  const int tid = threadIdx.x;
  const int w = tid >> 6, l = tid & 63;
  const int wr = w >> 2, wc = w & 3;
  const int nwg2d = gridDim.x * gridDim.y;
  const int lin = blockIdx.x + gridDim.x * blockIdx.y;
  const int wg = (lin & 7) * (nwg2d >> 3) + (lin >> 3);
  const int bx = wg % gridDim.x, by = wg / gridDim.x;
  const int aRow0 = by * 256, bRow0 = bx * 256;
  const long kbegB = (long)blockIdx.z * kLenB;
  const int nt = kLenB >> 7;
  i32x4 acc[8][4] = {};

  // prologue: t0.kh0(A,B), t0.kh1(A,B), t1.kh0(A,B) = 12 loads/wave
  stage_half8(A, aRow0, kbegB, &As[0][0][0], w, tid);
  stage_half8(BT, bRow0, kbegB, &Bs[0][0][0], w, tid);
  stage_half8(A, aRow0, kbegB + 64, &As[0][1][0], w, tid);
  stage_half8(BT, bRow0, kbegB + 64, &Bs[0][1][0], w, tid);
  {
    const int t1 = (nt > 1) ? 1 : 0;
    stage_half8(A, aRow0, kbegB + (long)t1 * 128, &As[1][0][0], w, tid);
    stage_half8(BT, bRow0, kbegB + (long)t1 * 128, &Bs[1][0][0], w, tid);
  }
  asm volatile("s_waitcnt vmcnt(4)" ::: "memory");
  SCHED0();
  BAR(); SCHED0();

  i32x4 av[8], bv[4];
  const int la = l & 15;
  for (int t = 0; t < nt; ++t) {
    const int d = t & 1;
    const signed char* Ah0 = &As[d][0][0];
    const signed char* Ah1 = &As[d][1][0];
    const signed char* Bh0 = &Bs[d][0][0];
    const signed char* Bh1 = &Bs[d][1][0];
    const int tt1 = (t + 1 < nt) ? t + 1 : nt - 1;
    const int tt2 = (t + 2 < nt) ? t + 2 : nt - 1;

#pragma unroll
    for (int m = 0; m < 8; ++m) av[m] = ldfragi(Ah0, wr * 128 + m * 16 + la, l);
#pragma unroll
    for (int n = 0; n < 4; ++n) bv[n] = ldfragi(Bh0, wc * 64 + n * 16 + la, l);
    stage_half8(A, aRow0, kbegB + (long)tt1 * 128 + 64, &As[d ^ 1][1][0], w, tid);
    stage_half8(BT, bRow0, kbegB + (long)tt1 * 128 + 64, &Bs[d ^ 1][1][0], w, tid);
    LGKM0();
    BAR(); SCHED0();          // all waves' kh0 reads done -> [d][0] overwrite-safe
    stage_half8(A, aRow0, kbegB + (long)tt2 * 128, &As[d][0][0], w, tid);
    stage_half8(BT, bRow0, kbegB + (long)tt2 * 128, &Bs[d][0][0], w, tid);
    __builtin_amdgcn_s_setprio(1);
#pragma unroll
    for (int m = 0; m < 8; ++m) {
#pragma unroll
      for (int n = 0; n < 4; ++n)
        acc[m][n] = __builtin_amdgcn_mfma_i32_16x16x64_i8(av[m], bv[n], acc[m][n], 0, 0, 0);
      av[m] = ldfragi(Ah1, wr * 128 + m * 16 + la, l);
    }
    __builtin_amdgcn_s_setprio(0);
#pragma unroll
    for (int n = 0; n < 4; ++n) bv[n] = ldfragi(Bh1, wc * 64 + n * 16 + la, l);
    LGKM0();
    __builtin_amdgcn_s_setprio(1);
#pragma unroll
    for (int m = 0; m < 8; ++m)
#pragma unroll
      for (int n = 0; n < 4; ++n)
        acc[m][n] = __builtin_amdgcn_mfma_i32_16x16x64_i8(av[m], bv[n], acc[m][n], 0, 0, 0);
    __builtin_amdgcn_s_setprio(0);
    asm volatile("s_waitcnt vmcnt(4)" ::: "memory");
    SCHED0();
    BAR(); SCHED0();
  }

  // C elem (row = base + (l>>4)*4 + j, col = base + (l&15)); dtype-independent map
  unsigned short* Pk = Pb + (long)blockIdx.z * NN * Nout;
  const int kz = blockIdx.z;
  const int lr = (l >> 4) * 4;
#pragma unroll
  for (int m = 0; m < 8; ++m)
#pragma unroll
    for (int n = 0; n < 4; ++n) {
      const int rowb = aRow0 + wr * 128 + m * 16 + lr;
      const int col = bRow0 + wc * 64 + n * 16 + la;
      const int cs = colsum[kz * Nout + col];
#pragma unroll
      for (int j = 0; j < 4; ++j)
        Pk[(long)(rowb + j) * Nout + col] = f2bf((float)(acc[m][n][j] + 127 * cs) * invscale);
    }
}

// ---------------- m97-style 128x128 bf16 GEMM for the small W-projection ----------------
// Epilogue: col<256 -> Q0 f32; col>=256 -> q12T[col-256][row] = i8(round(2048*dinv[row]*v))
__global__ __launch_bounds__(256) void gemm_w(
    const unsigned short* __restrict__ A, const unsigned short* __restrict__ BT,
    const int lda, const int ldbt, const int kLen, const int Nout,
    float* __restrict__ Q0, signed char* __restrict__ q12T,
    const float* __restrict__ dinv) {
  __shared__ unsigned short As[128 * 64];
  __shared__ unsigned short Bs[128 * 64];
  const int tid = threadIdx.x;
  const int w = tid >> 6, l = tid & 63;
  const int wr = w >> 1, wc = w & 1;
  const int nwg2d = gridDim.x * gridDim.y;
  const int lin = blockIdx.x + gridDim.x * blockIdx.y;
  const int wg = (lin & 7) * (nwg2d >> 3) + (lin >> 3);
  const int bx = wg % gridDim.x, by = wg / gridDim.x;
  const int aRow0 = by * 128, bRow0 = bx * 128;
  const int lrow8 = l >> 3;
  const int lk8 = (l & 7) * 8;
  f32x4 acc[4][4] = {};

  for (int k0 = 0; k0 < kLen; k0 += 64) {
    __syncthreads();
#pragma unroll
    for (int i = 0; i < 4; ++i) {
      const int ch = w * 4 + i;
      gload16(A + (long)(aRow0 + ch * 8 + lrow8) * lda + k0 + lk8, &As[ch * 512]);
      gload16(BT + (long)(bRow0 + ch * 8 + lrow8) * ldbt + k0 + lk8, &Bs[ch * 512]);
    }
    __syncthreads();
#pragma unroll
    for (int ks = 0; ks < 2; ++ks) {
      bf16x8 av[4], bv[4];
#pragma unroll
      for (int m = 0; m < 4; ++m)
        av[m] = *reinterpret_cast<const bf16x8*>(
            &As[(wr * 64 + m * 16 + (l & 15)) * 64 + ks * 32 + (l >> 4) * 8]);
#pragma unroll
      for (int n = 0; n < 4; ++n)
        bv[n] = *reinterpret_cast<const bf16x8*>(
            &Bs[(wc * 64 + n * 16 + (l & 15)) * 64 + ks * 32 + (l >> 4) * 8]);
#pragma unroll
      for (int m = 0; m < 4; ++m)
#pragma unroll
        for (int n = 0; n < 4; ++n)
          acc[m][n] = __builtin_amdgcn_mfma_f32_16x16x32_bf16(av[m], bv[n], acc[m][n], 0, 0, 0);
    }
  }

  const int lr = (l >> 4) * 4;
  const int lc = l & 15;
#pragma unroll
  for (int m = 0; m < 4; ++m)
#pragma unroll
    for (int n = 0; n < 4; ++n) {
      const int rowb = aRow0 + wr * 64 + m * 16 + lr;
      const int col = bRow0 + wc * 64 + n * 16 + lc;
      if (col < 256) {
#pragma unroll
        for (int j = 0; j < 4; ++j)
          Q0[(long)(rowb + j) * 256 + col] = acc[m][n][j];
      } else {
        signed char pv[4];
#pragma unroll
        for (int j = 0; j < 4; ++j) {
          float q = rintf(2048.f * dinv[rowb + j] * acc[m][n][j]);
          pv[j] = (signed char)(int)fminf(fmaxf(q, -127.f), 127.f);
        }
        *reinterpret_cast<int*>(&q12T[(long)(col - 256) * NN + rowb]) =
            *reinterpret_cast<int*>(pv);
      }
    }
}

// ---- colsumA: cs[kz][c] = sum over j in kz-chunk (2048) of q12T[c][j], kz<4, c<512 ----
__global__ void colsumA_kernel(const signed char* __restrict__ q12T, int* __restrict__ cs) {
  const int c = blockIdx.x, t = threadIdx.x;
  const uint4* row = reinterpret_cast<const uint4*>(q12T + (long)c * NN);
  uint4 v0 = row[t * 2], v1 = row[t * 2 + 1]; // bytes [32t, 32t+32)
  int s = sum4b(v0.x) + sum4b(v0.y) + sum4b(v0.z) + sum4b(v0.w) +
          sum4b(v1.x) + sum4b(v1.y) + sum4b(v1.z) + sum4b(v1.w);
  for (int o = 32; o; o >>= 1) s += __shfl_down(s, o, 64);
  if ((t & 63) == 0) cs[(t >> 6) * 512 + c] = s; // wave w == kz
}

// ---- colsumB: cs[kz][c] = sum over j in kz-chunk (1024) of bT2[c][j], kz<8, c<256 ----
__global__ void colsumB_kernel(const signed char* __restrict__ bT2, int* __restrict__ cs) {
  const int c = blockIdx.x, t = threadIdx.x;
  const uint4* row = reinterpret_cast<const uint4*>(bT2 + (long)c * NN);
  uint4 v0 = row[t * 2], v1 = row[t * 2 + 1];
  int s = sum4b(v0.x) + sum4b(v0.y) + sum4b(v0.z) + sum4b(v0.w) +
          sum4b(v1.x) + sum4b(v1.y) + sum4b(v1.z) + sum4b(v1.w);
  for (int o = 16; o; o >>= 1) s += __shfl_down(s, o, 64);
  if ((t & 31) == 0) cs[(t >> 5) * 256 + c] = s; // half-wave == kz
}

// ---- reduceA: S = sum_z Pb[z] over [8192][512] ----
// c<256: s1[r][c] = dinv[r]*S.  c>=256: bT2[c-256][r] = i8(round(131072*dinv^2*S)) (transposed)
__global__ void reduceA_kernel(const unsigned short* __restrict__ Pb, const int ks,
                               const float* __restrict__ dinv,
                               float* __restrict__ s1, signed char* __restrict__ bT2) {
  __shared__ float tile[64][65];
  const int c0 = blockIdx.x * 64;
  const int r0 = blockIdx.y * 64;
  const int t = threadIdx.x;
  if (c0 < 256) {
#pragma unroll
    for (int it = 0; it < 16; ++it) {
      int e = it * 256 + t;
      int r = e >> 6, c = e & 63;
      long off = (long)(r0 + r) * 512 + c0 + c;
      float S = 0.f;
      for (int z = 0; z < ks; ++z) S += bf2f(Pb[(long)z * NN * 512 + off]);
      s1[(long)(r0 + r) * 256 + c0 + c] = dinv[r0 + r] * S;
    }
  } else {
#pragma unroll
    for (int it = 0; it < 16; ++it) {
      int e = it * 256 + t;
      int r = e >> 6, c = e & 63;
      long off = (long)(r0 + r) * 512 + c0 + c;
      float S = 0.f;
      for (int z = 0; z < ks; ++z) S += bf2f(Pb[(long)z * NN * 512 + off]);
      const float di = dinv[r0 + r];
      tile[r][c] = di * di * S;
    }
    __syncthreads();
#pragma unroll
    for (int it = 0; it < 16; ++it) {
      int e = it * 256 + t;
      int rr = e >> 6, cc = e & 63;
      float q = rintf(131072.f * tile[cc][rr]);
      bT2[(long)(c0 - 256 + rr) * NN + r0 + cc] =
          (signed char)(int)fminf(fmaxf(q, -127.f), 127.f);
    }
  }
}

// ---- combine: h = relu(Q0 - s1 + 2*dinv[i]*sum_z P_B[z] + cheb_b); v = h @ gc2_W ----
__global__ void combine_u_kernel(const float* __restrict__ Q0, const float* __restrict__ s1,
                                 const unsigned short* __restrict__ Pb, const int ks,
                                 const float* __restrict__ dinv, const float* __restrict__ chebb,
                                 const float* __restrict__ gw, float* __restrict__ v) {
  const int i = blockIdx.x, t = threadIdx.x;
  float S = 0.f;
  for (int z = 0; z < ks; ++z) S += bf2f(Pb[(long)z * NN * 256 + (long)i * 256 + t]);
  float hv = Q0[(long)i * 256 + t] - s1[(long)i * 256 + t] + 2.f * dinv[i] * S + chebb[t];
  hv = hv > 0.f ? hv : 0.f;
  float p0 = hv * gw[t * 2];
  float p1 = hv * gw[t * 2 + 1];
  for (int o = 32; o; o >>= 1) {
    p0 += __shfl_down(p0, o, 64);
    p1 += __shfl_down(p1, o, 64);
  }
  __shared__ float s0[4], s1s[4];
  if ((t & 63) == 0) { s0[t >> 6] = p0; s1s[t >> 6] = p1; }
  __syncthreads();
  if (t == 0) {
    v[i * 2] = s0[0] + s0[1] + s0[2] + s0[3];
    v[i * 2 + 1] = s1s[0] + s1s[1] + s1s[2] + s1s[3];
  }
}

// ---- sumv: single block, deterministic tree-reduce of v over nodes (f64 accum) ----
__global__ void sumv_kernel(const float* __restrict__ v, float* __restrict__ sumv) {
  const int t = threadIdx.x;
  double a0 = 0.0, a1 = 0.0;
  for (int i = t; i < NN; i += 256) {
    a0 += (double)v[i * 2];
    a1 += (double)v[i * 2 + 1];
  }
  for (int o = 32; o; o >>= 1) {
    a0 += __shfl_down(a0, o, 64);
    a1 += __shfl_down(a1, o, 64);
  }
  __shared__ double s0[4], s1[4];
  if ((t & 63) == 0) { s0[t >> 6] = a0; s1[t >> 6] = a1; }
  __syncthreads();
  if (t == 0) {
    sumv[0] = (float)(s0[0] + s0[1] + s0[2] + s0[3]);
    sumv[1] = (float)(s1[0] + s1[1] + s1[2] + s1[3]);
  }
}

// ---- logits: 8 rows/block; logits[i][c] = (sum_j q_a[i][j]*v[j][c] + 127*sumv[c])/254 + gb[c] ----
__global__ void logits8_kernel(const signed char* __restrict__ A8,
                               const float* __restrict__ v,
                               const float* __restrict__ sumv,
                               const float* __restrict__ gb, float* __restrict__ logits) {
  const int g = blockIdx.x; // 1024 groups of 8 rows
  const int t = threadIdx.x;
  const float4* vv = reinterpret_cast<const float4*>(v);
  float a0[8] = {}, a1[8] = {};
#pragma unroll
  for (int it = 0; it < 2; ++it) {
    const int idx = it * 256 + t; // uint4 index within a row (512/row, 16 i8 each)
    float4 vs[8];
#pragma unroll
    for (int q = 0; q < 8; ++q) vs[q] = vv[idx * 8 + q];
#pragma unroll
    for (int r = 0; r < 8; ++r) {
      uint4 pk = reinterpret_cast<const uint4*>(A8 + (long)(g * 8 + r) * NN)[idx];
      unsigned uu[4] = {pk.x, pk.y, pk.z, pk.w};
#pragma unroll
      for (int q = 0; q < 4; ++q) {
        const unsigned u = uu[q];
        const float f0 = (float)(signed char)(u);
        const float f1 = (float)(signed char)(u >> 8);
        const float f2 = (float)(signed char)(u >> 16);
        const float f3 = (float)(signed char)(u >> 24);
        const float4 va = vs[q * 2], vb = vs[q * 2 + 1];
        a0[r] += f0 * va.x + f1 * va.z + f2 * vb.x + f3 * vb.z;
        a1[r] += f0 * va.y + f1 * va.w + f2 * vb.y + f3 * vb.w;
      }
    }
  }
  __shared__ float sm0[8][4], sm1[8][4];
#pragma unroll
  for (int r = 0; r < 8; ++r) {
    float x0 = a0[r], x1 = a1[r];
    for (int o = 32; o; o >>= 1) {
      x0 += __shfl_down(x0, o, 64);
      x1 += __shfl_down(x1, o, 64);
    }
    if ((t & 63) == 0) { sm0[r][t >> 6] = x0; sm1[r][t >> 6] = x1; }
  }
  __syncthreads();
  if (t < 8) {
    const float sv0 = sumv[0], sv1 = sumv[1];
    const float d0 = sm0[t][0] + sm0[t][1] + sm0[t][2] + sm0[t][3];
    const float d1 = sm1[t][0] + sm1[t][1] + sm1[t][2] + sm1[t][3];
    logits[(g * 8 + t) * 2] = (d0 + 127.f * sv0) * (1.f / 254.f) + gb[0];
    logits[(g * 8 + t) * 2 + 1] = (d1 + 127.f * sv1) * (1.f / 254.f) + gb[1];
  }
}

// ---------------- out[c] = max_i logits[i][c] ----------------
__global__ void maxpool_kernel(const float* __restrict__ logits, float* __restrict__ out) {
  const int t = threadIdx.x;
  float m0 = -3.4e38f, m1 = -3.4e38f;
  for (int i = t; i < NN; i += 256) {
    m0 = fmaxf(m0, logits[i * 2]);
    m1 = fmaxf(m1, logits[i * 2 + 1]);
  }
  for (int o = 32; o; o >>= 1) {
    m0 = fmaxf(m0, __shfl_down(m0, o, 64));
    m1 = fmaxf(m1, __shfl_down(m1, o, 64));
  }
  __shared__ float s0[4], s1[4];
  if ((t & 63) == 0) { s0[t >> 6] = m0; s1[t >> 6] = m1; }
  __syncthreads();
  if (t == 0) {
    out[0] = fmaxf(fmaxf(s0[0], s0[1]), fmaxf(s0[2], s0[3]));
    out[1] = fmaxf(fmaxf(s1[0], s1[1]), fmaxf(s1[2], s1[3]));
  }
}

extern "C" void kernel_launch(void* const* d_in, const int* in_sizes, int n_in,
                              void* d_out, int out_size, void* d_ws, size_t ws_size,
                              hipStream_t stream) {
  (void)in_sizes; (void)n_in; (void)out_size; (void)ws_size;
  const float* x = (const float*)d_in[0];       // [8192,512]
  const float* adj = (const float*)d_in[1];     // [8192,8192]
  const float* cheb_W = (const float*)d_in[2];  // [3,512,256]
  const float* cheb_b = (const float*)d_in[3];  // [256]
  const float* gc2_W = (const float*)d_in[4];   // [256,2]
  const float* gc2_b = (const float*)d_in[5];   // [2]
  float* out = (float*)d_out;                   // [2]

  char* ws = (char*)d_ws;
  signed char* A8      = (signed char*)(ws);                  // 64 MiB i8 adj (q=254a-127)
  unsigned short* xbf  = (unsigned short*)(ws + 67108864L);   // 8 MiB
  unsigned short* WTc  = (unsigned short*)(ws + 75497472L);   // 768 KiB [768][512]
  float* Q0            = (float*)(ws + 76546048L);            // 8 MiB f32 [8192][256]
  signed char* q12T    = (signed char*)(ws + 84934656L);      // 4 MiB i8 [512][8192]
  float* s1            = (float*)(ws + 89128960L);            // 8 MiB f32 [8192][256]
  signed char* bT2     = (signed char*)(ws + 97517568L);      // 2 MiB i8 [256][8192]
  float* dinv          = (float*)(ws + 99614720L);            // 32 KiB
  float* v             = (float*)(ws + 99647488L);            // 64 KiB
  float* logits        = (float*)(ws + 99713024L);            // 64 KiB
  int* colsumA         = (int*)(ws + 99778560L);              // 8 KiB [4][512]
  int* colsumB         = (int*)(ws + 99786752L);              // 8 KiB [8][256]
  float* sumv          = (float*)(ws + 99794944L);            // 8 B
  unsigned short* P    = (unsigned short*)(ws + 99803136L);   // 32 MiB bf16 partials

  const int ksA = 4, ksB = 8;
  const float invA = 1.f / (254.f * 2048.f);
  const float invB = 1.f / (254.f * 131072.f);

  // 1) A8 = i8(adj); dinv; xbf; WTc
  fusedprep_kernel<<<dim3(13824), dim3(256), 0, stream>>>(adj, x, cheb_W, A8, dinv, xbf, WTc);
  // 2) gemm_w: Q = xbf @ Wcat -> Q0 f32 (cols<256), q12T = i8(2048*dinv.*[q1|q2])^T
  gemm_w<<<dim3(6, 64, 1), dim3(256), 0, stream>>>(xbf, WTc, 512, 512, 512, 768, Q0, q12T, dinv);
  // 3) colsumA[kz][c]
  colsumA_kernel<<<dim3(512), dim3(256), 0, stream>>>(q12T, colsumA);
  // 4) GEMM_A (i8): P[kz] = dequant partials of adj @ (dinv.*[q1|q2])  [8192][512]
  gemm8i<<<dim3(2, 32, ksA), dim3(512), 0, stream>>>(A8, q12T, NN / ksA, 512, colsumA, invA, P);
  // 5) reduceA: s1 = dinv.*S[:,0:256]; bT2 = i8(131072*dinv^2.*S[:,256:512])^T
  reduceA_kernel<<<dim3(8, 128), dim3(256), 0, stream>>>(P, ksA, dinv, s1, bT2);
  // 6) colsumB[kz][c]
  colsumB_kernel<<<dim3(256), dim3(256), 0, stream>>>(bT2, colsumB);
  // 7) GEMM_B (i8): P[kz] = dequant partials of adj @ (dinv^2.*S2)  [8192][256]
  gemm8i<<<dim3(1, 32, ksB), dim3(512), 0, stream>>>(A8, bT2, NN / ksB, 256, colsumB, invB, P);
  // 8) h = relu(Q0 - s1 + 2*dinv.*sumP + b); v = h @ gc2_W
  combine_u_kernel<<<dim3(NN), dim3(256), 0, stream>>>(Q0, s1, P, ksB, dinv, cheb_b, gc2_W, v);
  // 9) sumv[c] = sum_i v[i][c]  (single block, deterministic)
  sumv_kernel<<<dim3(1), dim3(256), 0, stream>>>(v, sumv);
  // 10) logits = (q_adj @ v + 127*sumv)/254 + b
  logits8_kernel<<<dim3(1024), dim3(256), 0, stream>>>(A8, v, sumv, gc2_b, logits);
  maxpool_kernel<<<dim3(1), dim3(256), 0, stream>>>(logits, out);
}